// Round 1
// baseline (1949.490 us; speedup 1.0000x reference)
//
#include <hip/hip_runtime.h>

#define D 128

// ---------------------------------------------------------------------------
// Degree count: one thread per edge, float atomic on cnt[dst].
// ---------------------------------------------------------------------------
__global__ __launch_bounds__(256) void count_kernel(
    const int* __restrict__ dst, float* __restrict__ cnt, int E)
{
    int e = blockIdx.x * 256 + threadIdx.x;
    if (e < E) unsafeAtomicAdd(&cnt[dst[e]], 1.0f);
}

// ---------------------------------------------------------------------------
// Edge scatter: one wave (64 lanes) per edge. Lane l handles features
// [2l, 2l+1] -> full 512B row per wave, coalesced gather, 2 f32 atomics/lane.
// ---------------------------------------------------------------------------
__global__ __launch_bounds__(256) void scatter_kernel(
    const float* __restrict__ feat, const int* __restrict__ src,
    const int* __restrict__ dst, float* __restrict__ agg, int E)
{
    int tid  = blockIdx.x * 256 + threadIdx.x;
    int e    = tid >> 6;
    int lane = tid & 63;
    if (e >= E) return;
    int s = src[e];
    int d = dst[e];
    const float2 v = *reinterpret_cast<const float2*>(feat + s * D + 2 * lane);
    float* a = agg + d * D + 2 * lane;
    unsafeAtomicAdd(a,     v.x);
    unsafeAtomicAdd(a + 1, v.y);
}

// ---------------------------------------------------------------------------
// Fused SAGE linear: out = [relu]( (agg/max(cnt,1)) @ Wl + bl + xin @ Wr )
// Block: 256 threads, 64 rows x 128 cols output tile.
// W chunks (KC=32 rows of both Wl and Wr) staged in LDS (32 KB),
// A chunks (mean + x, 64x32 each) staged in LDS (18 KB).
// Thread t: cols {4*(t&15)..+3} u {64+4*(t&15)..+3}, rows 4*(t>>4)..+3.
// ---------------------------------------------------------------------------
__global__ __launch_bounds__(256, 2) void sage_gemm(
    const float* __restrict__ agg, const float* __restrict__ cnt,
    const float* __restrict__ xin,
    const float* __restrict__ Wl, const float* __restrict__ bl,
    const float* __restrict__ Wr,
    float* __restrict__ out, int N, int do_relu)
{
    constexpr int ROWS = 64, KC = 32, AP = 36;  // AP: padded row (16B-aligned, 2-way bank)
    __shared__ float sWl[KC][D];     // 16 KB
    __shared__ float sWr[KC][D];     // 16 KB
    __shared__ float sM[ROWS][AP];   // 9 KB
    __shared__ float sX[ROWS][AP];   // 9 KB

    const int t    = threadIdx.x;
    const int row0 = blockIdx.x * ROWS;
    const int tc   = t & 15;
    const int tr   = t >> 4;
    const int colA = 4 * tc;
    const int colB = 64 + 4 * tc;

    float acc[4][8];
#pragma unroll
    for (int r = 0; r < 4; ++r)
#pragma unroll
        for (int c = 0; c < 8; ++c) acc[r][c] = 0.0f;

    for (int k0 = 0; k0 < D; k0 += KC) {
        // --- stage W chunk: KC*D contiguous floats each ---
        const float4* gWl = reinterpret_cast<const float4*>(Wl + k0 * D);
        const float4* gWr = reinterpret_cast<const float4*>(Wr + k0 * D);
        float4* lWl = reinterpret_cast<float4*>(&sWl[0][0]);
        float4* lWr = reinterpret_cast<float4*>(&sWr[0][0]);
        for (int i = t; i < KC * D / 4; i += 256) {
            lWl[i] = gWl[i];
            lWr[i] = gWr[i];
        }
        // --- stage A chunk: rows row0..row0+63, cols k0..k0+KC-1 ---
        for (int i = t; i < ROWS * KC / 4; i += 256) {
            int r  = i >> 3;       // KC/4 = 8 float4 per row
            int c4 = i & 7;
            int gr = row0 + r;
            float4 mv = make_float4(0.f, 0.f, 0.f, 0.f);
            float4 xv = mv;
            if (gr < N) {
                float inv = 1.0f / fmaxf(cnt[gr], 1.0f);
                float4 a = *reinterpret_cast<const float4*>(agg + gr * D + k0 + 4 * c4);
                mv = make_float4(a.x * inv, a.y * inv, a.z * inv, a.w * inv);
                xv = *reinterpret_cast<const float4*>(xin + gr * D + k0 + 4 * c4);
            }
            *reinterpret_cast<float4*>(&sM[r][4 * c4]) = mv;
            *reinterpret_cast<float4*>(&sX[r][4 * c4]) = xv;
        }
        __syncthreads();

#pragma unroll 4
        for (int kk = 0; kk < KC; ++kk) {
            float wl[8], wr[8], m[4], xr[4];
            *reinterpret_cast<float4*>(&wl[0]) = *reinterpret_cast<const float4*>(&sWl[kk][colA]);
            *reinterpret_cast<float4*>(&wl[4]) = *reinterpret_cast<const float4*>(&sWl[kk][colB]);
            *reinterpret_cast<float4*>(&wr[0]) = *reinterpret_cast<const float4*>(&sWr[kk][colA]);
            *reinterpret_cast<float4*>(&wr[4]) = *reinterpret_cast<const float4*>(&sWr[kk][colB]);
#pragma unroll
            for (int r = 0; r < 4; ++r) {
                m[r]  = sM[4 * tr + r][kk];
                xr[r] = sX[4 * tr + r][kk];
            }
#pragma unroll
            for (int r = 0; r < 4; ++r)
#pragma unroll
                for (int c = 0; c < 8; ++c)
                    acc[r][c] += m[r] * wl[c] + xr[r] * wr[c];
        }
        __syncthreads();
    }

    // --- epilogue: + bias, optional relu, two float4 stores per row ---
#pragma unroll
    for (int r = 0; r < 4; ++r) {
        int gr = row0 + 4 * tr + r;
        if (gr >= N) continue;
        float4 oA, oB;
        oA.x = acc[r][0] + bl[colA + 0];
        oA.y = acc[r][1] + bl[colA + 1];
        oA.z = acc[r][2] + bl[colA + 2];
        oA.w = acc[r][3] + bl[colA + 3];
        oB.x = acc[r][4] + bl[colB + 0];
        oB.y = acc[r][5] + bl[colB + 1];
        oB.z = acc[r][6] + bl[colB + 2];
        oB.w = acc[r][7] + bl[colB + 3];
        if (do_relu) {
            oA.x = fmaxf(oA.x, 0.f); oA.y = fmaxf(oA.y, 0.f);
            oA.z = fmaxf(oA.z, 0.f); oA.w = fmaxf(oA.w, 0.f);
            oB.x = fmaxf(oB.x, 0.f); oB.y = fmaxf(oB.y, 0.f);
            oB.z = fmaxf(oB.z, 0.f); oB.w = fmaxf(oB.w, 0.f);
        }
        *reinterpret_cast<float4*>(out + gr * D + colA) = oA;
        *reinterpret_cast<float4*>(out + gr * D + colB) = oB;
    }
}

extern "C" void kernel_launch(void* const* d_in, const int* in_sizes, int n_in,
                              void* d_out, int out_size, void* d_ws, size_t ws_size,
                              hipStream_t stream) {
    const float* x   = (const float*)d_in[0];
    const int*   ei  = (const int*)d_in[1];
    const float* W1l = (const float*)d_in[2];
    const float* b1l = (const float*)d_in[3];
    const float* W1r = (const float*)d_in[4];
    const float* W2l = (const float*)d_in[5];
    const float* b2l = (const float*)d_in[6];
    const float* W2r = (const float*)d_in[7];
    float* out = (float*)d_out;

    const int N = in_sizes[0] / D;
    const int E = in_sizes[1] / 2;
    const int* src = ei;
    const int* dst = ei + E;

    float* agg = (float*)d_ws;
    float* cnt = agg + (size_t)N * D;
    float* h   = cnt + N;

    // zero agg + cnt (contiguous)
    hipMemsetAsync(agg, 0, (size_t)(N * D + N) * sizeof(float), stream);

    count_kernel<<<(E + 255) / 256, 256, 0, stream>>>(dst, cnt, E);
    scatter_kernel<<<(int)(((long long)E * 64 + 255) / 256), 256, 0, stream>>>(
        x, src, dst, agg, E);
    sage_gemm<<<(N + 63) / 64, 256, 0, stream>>>(agg, cnt, x, W1l, b1l, W1r, h, N, 1);

    hipMemsetAsync(agg, 0, (size_t)N * D * sizeof(float), stream);
    scatter_kernel<<<(int)(((long long)E * 64 + 255) / 256), 256, 0, stream>>>(
        h, src, dst, agg, E);
    sage_gemm<<<(N + 63) / 64, 256, 0, stream>>>(agg, cnt, h, W2l, b2l, W2r, out, N, 0);
}

// Round 2
// 585.391 us; speedup vs baseline: 3.3302x; 3.3302x over previous
//
#include <hip/hip_runtime.h>

#define D 128
constexpr int CHUNK = 2048;  // per-block scan chunk: 256 threads x 8

// ---------------------------------------------------------------------------
// 1. Degree histogram (int atomics)
// ---------------------------------------------------------------------------
__global__ __launch_bounds__(256) void hist_kernel(
    const int* __restrict__ dst, int* __restrict__ deg, int E)
{
    int e = blockIdx.x * 256 + threadIdx.x;
    if (e < E) atomicAdd(&deg[dst[e]], 1);
}

// ---------------------------------------------------------------------------
// 2a. Per-chunk exclusive scan of deg -> off, chunk totals -> chunkSum
// ---------------------------------------------------------------------------
__global__ __launch_bounds__(256) void scanA_kernel(
    const int* __restrict__ deg, int* __restrict__ off,
    int* __restrict__ chunkSum, int N)
{
    __shared__ int s[256];
    const int t = threadIdx.x;
    const int base = blockIdx.x * CHUNK + t * 8;
    int v[8], sum = 0;
#pragma unroll
    for (int i = 0; i < 8; ++i) {
        int idx = base + i;
        v[i] = (idx < N) ? deg[idx] : 0;
        sum += v[i];
    }
    s[t] = sum;
    __syncthreads();
    // inclusive Hillis-Steele scan over 256 thread sums
    for (int o = 1; o < 256; o <<= 1) {
        int y = (t >= o) ? s[t - o] : 0;
        __syncthreads();
        s[t] += y;
        __syncthreads();
    }
    int excl = s[t] - sum;  // exclusive prefix of this thread within chunk
#pragma unroll
    for (int i = 0; i < 8; ++i) {
        int idx = base + i;
        if (idx < N) off[idx] = excl;
        excl += v[i];
    }
    if (t == 0) chunkSum[blockIdx.x] = s[255];
}

// ---------------------------------------------------------------------------
// 2b. Exclusive scan of chunk sums (tiny; serial on one thread)
// ---------------------------------------------------------------------------
__global__ void scanB_kernel(int* __restrict__ chunkSum, int nChunks)
{
    if (threadIdx.x == 0 && blockIdx.x == 0) {
        int run = 0;
        for (int i = 0; i < nChunks; ++i) {
            int v = chunkSum[i];
            chunkSum[i] = run;
            run += v;
        }
    }
}

// ---------------------------------------------------------------------------
// 2c. Add chunk offsets; produce final off[] and cursor[] copy
// ---------------------------------------------------------------------------
__global__ __launch_bounds__(256) void scanC_kernel(
    int* __restrict__ off, int* __restrict__ cursor,
    const int* __restrict__ chunkSum, int N)
{
    int i = blockIdx.x * 256 + threadIdx.x;
    if (i < N) {
        int o = off[i] + chunkSum[i / CHUNK];
        off[i] = o;
        cursor[i] = o;
    }
}

// ---------------------------------------------------------------------------
// 3. CSR fill: csr_src grouped by dst
// ---------------------------------------------------------------------------
__global__ __launch_bounds__(256) void fill_kernel(
    const int* __restrict__ src, const int* __restrict__ dst,
    int* __restrict__ cursor, int* __restrict__ csr_src, int E)
{
    int e = blockIdx.x * 256 + threadIdx.x;
    if (e < E) {
        int p = atomicAdd(&cursor[dst[e]], 1);
        csr_src[p] = src[e];
    }
}

// ---------------------------------------------------------------------------
// 4. Gather-mean: one wave per node. Lane l accumulates features [2l,2l+1].
//    After fill, cursor[n] == off[n] + deg[n] (end pointer).
// ---------------------------------------------------------------------------
__global__ __launch_bounds__(256) void gather_kernel(
    const float* __restrict__ feat, const int* __restrict__ off,
    const int* __restrict__ endp, const int* __restrict__ csr_src,
    float* __restrict__ mean, int N)
{
    int tid  = blockIdx.x * 256 + threadIdx.x;
    int n    = tid >> 6;
    int lane = tid & 63;
    if (n >= N) return;
    int begin = off[n];
    int end   = endp[n];
    float2 acc = make_float2(0.f, 0.f);
    for (int j = begin; j < end; ++j) {
        int s = csr_src[j];
        float2 v = *reinterpret_cast<const float2*>(feat + (size_t)s * D + 2 * lane);
        acc.x += v.x;
        acc.y += v.y;
    }
    float invd = 1.0f / (float)max(end - begin, 1);
    acc.x *= invd;
    acc.y *= invd;
    *reinterpret_cast<float2*>(mean + (size_t)n * D + 2 * lane) = acc;
}

// ---------------------------------------------------------------------------
// 5. Fused SAGE linear: out = [relu]( mean @ Wl + bl + xin @ Wr )
// ---------------------------------------------------------------------------
__global__ __launch_bounds__(256, 2) void sage_gemm(
    const float* __restrict__ mean, const float* __restrict__ xin,
    const float* __restrict__ Wl, const float* __restrict__ bl,
    const float* __restrict__ Wr,
    float* __restrict__ out, int N, int do_relu)
{
    constexpr int ROWS = 64, KC = 32, AP = 36;
    __shared__ float sWl[KC][D];
    __shared__ float sWr[KC][D];
    __shared__ float sM[ROWS][AP];
    __shared__ float sX[ROWS][AP];

    const int t    = threadIdx.x;
    const int row0 = blockIdx.x * ROWS;
    const int tc   = t & 15;
    const int tr   = t >> 4;
    const int colA = 4 * tc;
    const int colB = 64 + 4 * tc;

    float acc[4][8];
#pragma unroll
    for (int r = 0; r < 4; ++r)
#pragma unroll
        for (int c = 0; c < 8; ++c) acc[r][c] = 0.0f;

    for (int k0 = 0; k0 < D; k0 += KC) {
        const float4* gWl = reinterpret_cast<const float4*>(Wl + k0 * D);
        const float4* gWr = reinterpret_cast<const float4*>(Wr + k0 * D);
        float4* lWl = reinterpret_cast<float4*>(&sWl[0][0]);
        float4* lWr = reinterpret_cast<float4*>(&sWr[0][0]);
        for (int i = t; i < KC * D / 4; i += 256) {
            lWl[i] = gWl[i];
            lWr[i] = gWr[i];
        }
        for (int i = t; i < ROWS * KC / 4; i += 256) {
            int r  = i >> 3;
            int c4 = i & 7;
            int gr = row0 + r;
            float4 mv = make_float4(0.f, 0.f, 0.f, 0.f);
            float4 xv = mv;
            if (gr < N) {
                mv = *reinterpret_cast<const float4*>(mean + (size_t)gr * D + k0 + 4 * c4);
                xv = *reinterpret_cast<const float4*>(xin + (size_t)gr * D + k0 + 4 * c4);
            }
            *reinterpret_cast<float4*>(&sM[r][4 * c4]) = mv;
            *reinterpret_cast<float4*>(&sX[r][4 * c4]) = xv;
        }
        __syncthreads();

#pragma unroll 4
        for (int kk = 0; kk < KC; ++kk) {
            float wl[8], wr[8], m[4], xr[4];
            *reinterpret_cast<float4*>(&wl[0]) = *reinterpret_cast<const float4*>(&sWl[kk][colA]);
            *reinterpret_cast<float4*>(&wl[4]) = *reinterpret_cast<const float4*>(&sWl[kk][colB]);
            *reinterpret_cast<float4*>(&wr[0]) = *reinterpret_cast<const float4*>(&sWr[kk][colA]);
            *reinterpret_cast<float4*>(&wr[4]) = *reinterpret_cast<const float4*>(&sWr[kk][colB]);
#pragma unroll
            for (int r = 0; r < 4; ++r) {
                m[r]  = sM[4 * tr + r][kk];
                xr[r] = sX[4 * tr + r][kk];
            }
#pragma unroll
            for (int r = 0; r < 4; ++r)
#pragma unroll
                for (int c = 0; c < 8; ++c)
                    acc[r][c] += m[r] * wl[c] + xr[r] * wr[c];
        }
        __syncthreads();
    }

#pragma unroll
    for (int r = 0; r < 4; ++r) {
        int gr = row0 + 4 * tr + r;
        if (gr >= N) continue;
        float4 oA, oB;
        oA.x = acc[r][0] + bl[colA + 0];
        oA.y = acc[r][1] + bl[colA + 1];
        oA.z = acc[r][2] + bl[colA + 2];
        oA.w = acc[r][3] + bl[colA + 3];
        oB.x = acc[r][4] + bl[colB + 0];
        oB.y = acc[r][5] + bl[colB + 1];
        oB.z = acc[r][6] + bl[colB + 2];
        oB.w = acc[r][7] + bl[colB + 3];
        if (do_relu) {
            oA.x = fmaxf(oA.x, 0.f); oA.y = fmaxf(oA.y, 0.f);
            oA.z = fmaxf(oA.z, 0.f); oA.w = fmaxf(oA.w, 0.f);
            oB.x = fmaxf(oB.x, 0.f); oB.y = fmaxf(oB.y, 0.f);
            oB.z = fmaxf(oB.z, 0.f); oB.w = fmaxf(oB.w, 0.f);
        }
        *reinterpret_cast<float4*>(out + (size_t)gr * D + colA) = oA;
        *reinterpret_cast<float4*>(out + (size_t)gr * D + colB) = oB;
    }
}

extern "C" void kernel_launch(void* const* d_in, const int* in_sizes, int n_in,
                              void* d_out, int out_size, void* d_ws, size_t ws_size,
                              hipStream_t stream) {
    const float* x   = (const float*)d_in[0];
    const int*   ei  = (const int*)d_in[1];
    const float* W1l = (const float*)d_in[2];
    const float* b1l = (const float*)d_in[3];
    const float* W1r = (const float*)d_in[4];
    const float* W2l = (const float*)d_in[5];
    const float* b2l = (const float*)d_in[6];
    const float* W2r = (const float*)d_in[7];
    float* out = (float*)d_out;

    const int N = in_sizes[0] / D;
    const int E = in_sizes[1] / 2;
    const int* src = ei;
    const int* dst = ei + E;

    // workspace layout (floats first, then ints)
    float* mean = (float*)d_ws;                    // N*D
    float* h    = mean + (size_t)N * D;            // N*D
    int*   deg     = (int*)(h + (size_t)N * D);    // N
    int*   off     = deg + N;                      // N
    int*   cursor  = off + N;                      // N
    int*   csr_src = cursor + N;                   // E
    int*   chunkSum = csr_src + E;                 // nChunks

    const int nChunks = (N + CHUNK - 1) / CHUNK;

    // --- CSR build (once, reused by both layers) ---
    hipMemsetAsync(deg, 0, (size_t)N * sizeof(int), stream);
    hist_kernel<<<(E + 255) / 256, 256, 0, stream>>>(dst, deg, E);
    scanA_kernel<<<nChunks, 256, 0, stream>>>(deg, off, chunkSum, N);
    scanB_kernel<<<1, 64, 0, stream>>>(chunkSum, nChunks);
    scanC_kernel<<<(N + 255) / 256, 256, 0, stream>>>(off, cursor, chunkSum, N);
    fill_kernel<<<(E + 255) / 256, 256, 0, stream>>>(src, dst, cursor, csr_src, E);
    // after fill: cursor[n] == off[n] + deg[n]  (end pointers)

    const int gatherBlocks = (int)(((long long)N * 64 + 255) / 256);

    // --- layer 1 ---
    gather_kernel<<<gatherBlocks, 256, 0, stream>>>(x, off, cursor, csr_src, mean, N);
    sage_gemm<<<(N + 63) / 64, 256, 0, stream>>>(mean, x, W1l, b1l, W1r, h, N, 1);

    // --- layer 2 ---
    gather_kernel<<<gatherBlocks, 256, 0, stream>>>(h, off, cursor, csr_src, mean, N);
    sage_gemm<<<(N + 63) / 64, 256, 0, stream>>>(mean, h, W2l, b2l, W2r, out, N, 0);
}

// Round 3
// 307.361 us; speedup vs baseline: 6.3427x; 1.9046x over previous
//
#include <hip/hip_runtime.h>

#define D 128
constexpr int CHUNK = 2048;

typedef __bf16 bf16x8 __attribute__((ext_vector_type(8)));
typedef float f32x4 __attribute__((ext_vector_type(4)));

__device__ __forceinline__ unsigned short f2bf(float f) {
    unsigned int u = __float_as_uint(f);
    unsigned int r = (u + 0x7fffu + ((u >> 16) & 1u)) >> 16;
    return (unsigned short)r;
}

// ---------------------------------------------------------------------------
// CSR build (unchanged from round 2)
// ---------------------------------------------------------------------------
__global__ __launch_bounds__(256) void hist_kernel(
    const int* __restrict__ dst, int* __restrict__ deg, int E)
{
    int e = blockIdx.x * 256 + threadIdx.x;
    if (e < E) atomicAdd(&deg[dst[e]], 1);
}

__global__ __launch_bounds__(256) void scanA_kernel(
    const int* __restrict__ deg, int* __restrict__ off,
    int* __restrict__ chunkSum, int N)
{
    __shared__ int s[256];
    const int t = threadIdx.x;
    const int base = blockIdx.x * CHUNK + t * 8;
    int v[8], sum = 0;
#pragma unroll
    for (int i = 0; i < 8; ++i) {
        int idx = base + i;
        v[i] = (idx < N) ? deg[idx] : 0;
        sum += v[i];
    }
    s[t] = sum;
    __syncthreads();
    for (int o = 1; o < 256; o <<= 1) {
        int y = (t >= o) ? s[t - o] : 0;
        __syncthreads();
        s[t] += y;
        __syncthreads();
    }
    int excl = s[t] - sum;
#pragma unroll
    for (int i = 0; i < 8; ++i) {
        int idx = base + i;
        if (idx < N) off[idx] = excl;
        excl += v[i];
    }
    if (t == 0) chunkSum[blockIdx.x] = s[255];
}

__global__ void scanB_kernel(int* __restrict__ chunkSum, int nChunks)
{
    if (threadIdx.x == 0 && blockIdx.x == 0) {
        int run = 0;
        for (int i = 0; i < nChunks; ++i) {
            int v = chunkSum[i];
            chunkSum[i] = run;
            run += v;
        }
    }
}

__global__ __launch_bounds__(256) void scanC_kernel(
    int* __restrict__ off, int* __restrict__ cursor,
    const int* __restrict__ chunkSum, int N)
{
    int i = blockIdx.x * 256 + threadIdx.x;
    if (i < N) {
        int o = off[i] + chunkSum[i / CHUNK];
        off[i] = o;
        cursor[i] = o;
    }
}

__global__ __launch_bounds__(256) void fill_kernel(
    const int* __restrict__ src, const int* __restrict__ dst,
    int* __restrict__ cursor, int* __restrict__ csr_src, int E)
{
    int e = blockIdx.x * 256 + threadIdx.x;
    if (e < E) {
        int p = atomicAdd(&cursor[dst[e]], 1);
        csr_src[p] = src[e];
    }
}

// ---------------------------------------------------------------------------
// fp32 -> bf16 convert (vectorized)
// ---------------------------------------------------------------------------
__global__ __launch_bounds__(256) void f2b_kernel(
    const float* __restrict__ in, unsigned short* __restrict__ out, int n4)
{
    int i = blockIdx.x * 256 + threadIdx.x;
    if (i < n4) {
        float4 v = reinterpret_cast<const float4*>(in)[i];
        ushort4 o;
        o.x = f2bf(v.x); o.y = f2bf(v.y); o.z = f2bf(v.z); o.w = f2bf(v.w);
        reinterpret_cast<ushort4*>(out)[i] = o;
    }
}

// ---------------------------------------------------------------------------
// Pack W (fp32 row-major [K][N]) into MFMA B-fragment order, bf16.
// Frag (layer, wsel, kt, ct): lane l, elem j holds W[kt*32 + (l>>4)*8 + j][ct*16 + (l&15)]
// grid: 128 blocks x 64 threads (2 layers x 2 W x 4 ktiles x 8 coltiles)
// ---------------------------------------------------------------------------
__global__ __launch_bounds__(64) void pack_kernel(
    const float* __restrict__ W1l, const float* __restrict__ W1r,
    const float* __restrict__ W2l, const float* __restrict__ W2r,
    unsigned short* __restrict__ Wpack)
{
    int b = blockIdx.x, l = threadIdx.x;
    int layer = b >> 6, wsel = (b >> 5) & 1, kt = (b >> 3) & 3, ct = b & 7;
    const float* W = layer ? (wsel ? W2r : W2l) : (wsel ? W1r : W1l);
    int k0  = kt * 32 + (l >> 4) * 8;
    int col = ct * 16 + (l & 15);
    unsigned short tmp[8];
#pragma unroll
    for (int j = 0; j < 8; ++j) tmp[j] = f2bf(W[(k0 + j) * D + col]);
    size_t fbase = (((size_t)layer * 64 + wsel * 32 + kt * 8 + ct) * 64 + l) * 8;
    uint4 o;
    o.x = (unsigned)tmp[0] | ((unsigned)tmp[1] << 16);
    o.y = (unsigned)tmp[2] | ((unsigned)tmp[3] << 16);
    o.z = (unsigned)tmp[4] | ((unsigned)tmp[5] << 16);
    o.w = (unsigned)tmp[6] | ((unsigned)tmp[7] << 16);
    *reinterpret_cast<uint4*>(Wpack + fbase) = o;
}

// ---------------------------------------------------------------------------
// Gather-mean in bf16: one wave per node, lane l owns features [2l, 2l+1].
// fp32 accumulate, bf16 output.
// ---------------------------------------------------------------------------
__global__ __launch_bounds__(256) void gather_bf16(
    const unsigned short* __restrict__ feat, const int* __restrict__ off,
    const int* __restrict__ endp, const int* __restrict__ csr,
    unsigned short* __restrict__ mean, int N)
{
    int tid  = blockIdx.x * 256 + threadIdx.x;
    int n    = tid >> 6;
    int lane = tid & 63;
    if (n >= N) return;
    int b = off[n], e = endp[n];
    const unsigned short* fp = feat + lane * 2;
    float ax = 0.f, ay = 0.f, bx = 0.f, by = 0.f;
    int j = b;
    for (; j + 1 < e; j += 2) {
        unsigned v0 = *reinterpret_cast<const unsigned*>(fp + (size_t)csr[j] * D);
        unsigned v1 = *reinterpret_cast<const unsigned*>(fp + (size_t)csr[j + 1] * D);
        ax += __uint_as_float(v0 << 16);
        ay += __uint_as_float(v0 & 0xffff0000u);
        bx += __uint_as_float(v1 << 16);
        by += __uint_as_float(v1 & 0xffff0000u);
    }
    if (j < e) {
        unsigned v0 = *reinterpret_cast<const unsigned*>(fp + (size_t)csr[j] * D);
        ax += __uint_as_float(v0 << 16);
        ay += __uint_as_float(v0 & 0xffff0000u);
    }
    ax += bx; ay += by;
    float invd = 1.0f / (float)max(e - b, 1);
    ax *= invd; ay *= invd;
    unsigned o = (unsigned)f2bf(ax) | ((unsigned)f2bf(ay) << 16);
    *reinterpret_cast<unsigned*>(mean + (size_t)n * D + lane * 2) = o;
}

// ---------------------------------------------------------------------------
// MFMA SAGE linear: out = [relu]( mean @ Wl + bl + xin @ Wr ), all bf16 in.
// K=256 logical (mean|xin). 256 threads = 4 waves; wave wc owns cols 32wc..+31
// (2 coltiles), holds its 16 B-frags in registers for the whole M-loop.
// A-tile (16 rows x 512B) staged in LDS, XOR-swizzled, double-buffered.
// ---------------------------------------------------------------------------
template <int RELU, int OUT_BF16>
__global__ __launch_bounds__(256, 2) void sage_mfma(
    const unsigned short* __restrict__ meanb,
    const unsigned short* __restrict__ xb,
    const unsigned short* __restrict__ Wpack,
    const float* __restrict__ bl,
    void* __restrict__ outv, int Mtiles, int TPB)
{
    __shared__ __align__(16) char sbuf[2][8192];
    const int t    = threadIdx.x;
    const int lane = t & 63;
    const int wc   = t >> 6;
    const int l15  = lane & 15;
    const int lhi  = lane >> 4;

    // --- B-fragments: 2 coltiles x 8 ktiles, resident in VGPRs ---
    bf16x8 bfrag[2][8];
#pragma unroll
    for (int ktt = 0; ktt < 8; ++ktt) {
        int wsel = ktt >> 2, kt = ktt & 3;
#pragma unroll
        for (int c = 0; c < 2; ++c) {
            int ct = wc * 2 + c;
            size_t fbase = ((size_t)(wsel * 32 + kt * 8 + ct) * 64 + lane) * 8;
            bfrag[c][ktt] = *reinterpret_cast<const bf16x8*>(Wpack + fbase);
        }
    }
    float bias[2];
    bias[0] = bl[wc * 32 + l15];
    bias[1] = bl[wc * 32 + 16 + l15];

    int tile0 = blockIdx.x * TPB;
    if (tile0 >= Mtiles) return;
    int tend = min(tile0 + TPB, Mtiles);

    // staging geometry: thread t stages unit (r = t>>4, q = t&15) of both parts
    const int sr = t >> 4;
    const int sq = t & 15;
    const int ss = sq ^ (sr & 7);
    char* dstM = &sbuf[0][sr * 256 + ss * 16];
    char* dstX = &sbuf[0][4096 + sr * 256 + ss * 16];

    // prologue: stage tile0 into buf 0
    {
        size_t gofs = (size_t)(tile0 * 16 + sr) * D + sq * 8;
        *reinterpret_cast<uint4*>(dstM) = *reinterpret_cast<const uint4*>(meanb + gofs);
        *reinterpret_cast<uint4*>(dstX) = *reinterpret_cast<const uint4*>(xb + gofs);
    }
    int cur = 0;

    for (int it = tile0; it < tend; ++it) {
        __syncthreads();  // sbuf[cur] ready
        const bool pf = (it + 1 < tend);
        uint4 mv, xv;
        if (pf) {  // issue next-tile global loads early (T14)
            size_t gofs = (size_t)((it + 1) * 16 + sr) * D + sq * 8;
            mv = *reinterpret_cast<const uint4*>(meanb + gofs);
            xv = *reinterpret_cast<const uint4*>(xb + gofs);
        }

        // --- compute from sbuf[cur] ---
        f32x4 acc0 = {0.f, 0.f, 0.f, 0.f};
        f32x4 acc1 = {0.f, 0.f, 0.f, 0.f};
        const char* base = sbuf[cur];
#pragma unroll
        for (int ktt = 0; ktt < 8; ++ktt) {
            int p = ktt >> 2, kt = ktt & 3;
            int q = kt * 4 + lhi;
            int byteoff = p * 4096 + l15 * 256 + ((q ^ (l15 & 7)) * 16);
            bf16x8 a = *reinterpret_cast<const bf16x8*>(base + byteoff);
            acc0 = __builtin_amdgcn_mfma_f32_16x16x32_bf16(a, bfrag[0][ktt], acc0, 0, 0, 0);
            acc1 = __builtin_amdgcn_mfma_f32_16x16x32_bf16(a, bfrag[1][ktt], acc1, 0, 0, 0);
        }

        // --- epilogue: bias, relu, store ---
        int rbase = it * 16 + lhi * 4;
#pragma unroll
        for (int c = 0; c < 2; ++c) {
            int col = wc * 32 + c * 16 + l15;
            const f32x4& a = c ? acc1 : acc0;
#pragma unroll
            for (int r = 0; r < 4; ++r) {
                float v = a[r] + bias[c];
                if (RELU) v = fmaxf(v, 0.f);
                if (OUT_BF16) {
                    ((unsigned short*)outv)[(size_t)(rbase + r) * D + col] = f2bf(v);
                } else {
                    ((float*)outv)[(size_t)(rbase + r) * D + col] = v;
                }
            }
        }

        if (pf) {  // write next tile into the other buffer (no barrier needed)
            char* dM = dstM + (cur ^ 1) * 8192;
            char* dX = dstX + (cur ^ 1) * 8192;
            *reinterpret_cast<uint4*>(dM) = mv;
            *reinterpret_cast<uint4*>(dX) = xv;
            cur ^= 1;
        }
    }
}

extern "C" void kernel_launch(void* const* d_in, const int* in_sizes, int n_in,
                              void* d_out, int out_size, void* d_ws, size_t ws_size,
                              hipStream_t stream) {
    const float* x   = (const float*)d_in[0];
    const int*   ei  = (const int*)d_in[1];
    const float* W1l = (const float*)d_in[2];
    const float* b1l = (const float*)d_in[3];
    const float* W1r = (const float*)d_in[4];
    const float* W2l = (const float*)d_in[5];
    const float* b2l = (const float*)d_in[6];
    const float* W2r = (const float*)d_in[7];
    float* out = (float*)d_out;

    const int N = in_sizes[0] / D;
    const int E = in_sizes[1] / 2;
    const int* src = ei;
    const int* dst = ei + E;

    // workspace layout: bf16 arrays (16B aligned), then Wpack, then ints
    unsigned short* xb    = (unsigned short*)d_ws;          // N*D bf16
    unsigned short* meanb = xb + (size_t)N * D;             // N*D
    unsigned short* hb    = meanb + (size_t)N * D;          // N*D
    unsigned short* Wpack = hb + (size_t)N * D;             // 2*64*512 = 65536
    int* deg      = (int*)(Wpack + 65536);                  // N
    int* off      = deg + N;                                // N
    int* cursor   = off + N;                                // N
    int* csr_src  = cursor + N;                             // E
    int* chunkSum = csr_src + E;                            // nChunks

    const int nChunks = (N + CHUNK - 1) / CHUNK;
    const int Mtiles  = (N + 15) / 16;
    const int TPB     = 8;
    const int gemmGrid = (Mtiles + TPB - 1) / TPB;
    const int gatherBlocks = (int)(((long long)N * 64 + 255) / 256);

    // --- CSR build ---
    hipMemsetAsync(deg, 0, (size_t)N * sizeof(int), stream);
    hist_kernel<<<(E + 255) / 256, 256, 0, stream>>>(dst, deg, E);
    scanA_kernel<<<nChunks, 256, 0, stream>>>(deg, off, chunkSum, N);
    scanB_kernel<<<1, 64, 0, stream>>>(chunkSum, nChunks);
    scanC_kernel<<<(N + 255) / 256, 256, 0, stream>>>(off, cursor, chunkSum, N);
    fill_kernel<<<(E + 255) / 256, 256, 0, stream>>>(src, dst, cursor, csr_src, E);

    // --- precision prep ---
    f2b_kernel<<<((N * D / 4) + 255) / 256, 256, 0, stream>>>(x, xb, N * D / 4);
    pack_kernel<<<128, 64, 0, stream>>>(W1l, W1r, W2l, W2r, Wpack);

    // --- layer 1 ---
    gather_bf16<<<gatherBlocks, 256, 0, stream>>>(xb, off, cursor, csr_src, meanb, N);
    sage_mfma<1, 1><<<gemmGrid, 256, 0, stream>>>(meanb, xb, Wpack, b1l, hb, Mtiles, TPB);

    // --- layer 2 ---
    gather_bf16<<<gatherBlocks, 256, 0, stream>>>(hb, off, cursor, csr_src, meanb, N);
    sage_mfma<0, 0><<<gemmGrid, 256, 0, stream>>>(meanb, hb, Wpack + 32768, b2l, out, Mtiles, TPB);
}

// Round 4
// 280.943 us; speedup vs baseline: 6.9391x; 1.0940x over previous
//
#include <hip/hip_runtime.h>

#define D 128
constexpr int CHUNK = 2048;

typedef __bf16 bf16x8 __attribute__((ext_vector_type(8)));
typedef float f32x4 __attribute__((ext_vector_type(4)));

__device__ __forceinline__ unsigned short f2bf(float f) {
    unsigned int u = __float_as_uint(f);
    unsigned int r = (u + 0x7fffu + ((u >> 16) & 1u)) >> 16;
    return (unsigned short)r;
}

// ---------------------------------------------------------------------------
// 1. Degree histogram (int atomics)
// ---------------------------------------------------------------------------
__global__ __launch_bounds__(256) void hist_kernel(
    const int* __restrict__ dst, int* __restrict__ deg, int E)
{
    int e = blockIdx.x * 256 + threadIdx.x;
    if (e < E) atomicAdd(&deg[dst[e]], 1);
}

// ---------------------------------------------------------------------------
// 2a. Per-chunk exclusive scan of deg -> off, chunk totals -> chunkSum
// ---------------------------------------------------------------------------
__global__ __launch_bounds__(256) void scanA_kernel(
    const int* __restrict__ deg, int* __restrict__ off,
    int* __restrict__ chunkSum, int N)
{
    __shared__ int s[256];
    const int t = threadIdx.x;
    const int base = blockIdx.x * CHUNK + t * 8;
    int v[8], sum = 0;
#pragma unroll
    for (int i = 0; i < 8; ++i) {
        int idx = base + i;
        v[i] = (idx < N) ? deg[idx] : 0;
        sum += v[i];
    }
    s[t] = sum;
    __syncthreads();
    for (int o = 1; o < 256; o <<= 1) {
        int y = (t >= o) ? s[t - o] : 0;
        __syncthreads();
        s[t] += y;
        __syncthreads();
    }
    int excl = s[t] - sum;
#pragma unroll
    for (int i = 0; i < 8; ++i) {
        int idx = base + i;
        if (idx < N) off[idx] = excl;
        excl += v[i];
    }
    if (t == 0) chunkSum[blockIdx.x] = s[255];
}

// ---------------------------------------------------------------------------
// 2b. Add chunk prefix (computed in-block via wave reduce over <=64 chunks);
//     produce final off[] and cursor[] copy.  (scanB eliminated)
// ---------------------------------------------------------------------------
__global__ __launch_bounds__(256) void scanC_kernel(
    int* __restrict__ off, int* __restrict__ cursor,
    const int* __restrict__ chunkSum, int N, int nChunks)
{
    __shared__ int sprefix;
    const int c = (blockIdx.x * 256) / CHUNK;  // uniform: 256 | 2048
    if (threadIdx.x < 64) {
        int l = threadIdx.x;
        int v = (l < c && l < nChunks) ? chunkSum[l] : 0;
#pragma unroll
        for (int o = 32; o; o >>= 1) v += __shfl_down(v, o, 64);
        if (l == 0) sprefix = v;
    }
    __syncthreads();
    int i = blockIdx.x * 256 + threadIdx.x;
    if (i < N) {
        int o = off[i] + sprefix;
        off[i] = o;
        cursor[i] = o;
    }
}

// ---------------------------------------------------------------------------
// 3. XCD-partitioned CSR fill. Group g = blockIdx&7 (round-robin -> XCD g)
//    handles only dst in [g*npg, (g+1)*npg): its csr writes + cursor atomics
//    stay in one XCD's L2 -> full line merge, no cross-XCD write sharing.
//    Each group scans the whole edge list (reads are L3-absorbed).
// ---------------------------------------------------------------------------
__global__ __launch_bounds__(256) void fill8_kernel(
    const int* __restrict__ src, const int* __restrict__ dst,
    int* __restrict__ cursor, int* __restrict__ csr_src,
    int E, int npg, int segSpan)
{
    const int g   = blockIdx.x & 7;
    const int seg = blockIdx.x >> 3;
    const int lo  = g * npg;
    const int hi  = lo + npg;
    const int e0  = seg * segSpan;
    const int e1  = min(e0 + segSpan, E);
    for (int e = e0 + threadIdx.x; e < e1; e += 256) {
        int d = dst[e];
        if (d >= lo && d < hi) {
            int p = atomicAdd(&cursor[d], 1);
            csr_src[p] = src[e];
        }
    }
}

// ---------------------------------------------------------------------------
// 4. Fused prep: blocks [0,32) pack W into MFMA B-fragment order (bf16);
//    blocks [32,..) convert x fp32->bf16.
// Frag (layer,wsel,kt,ct): lane l elem j = W[kt*32+(l>>4)*8+j][ct*16+(l&15)]
// ---------------------------------------------------------------------------
__global__ __launch_bounds__(256) void prep_kernel(
    const float* __restrict__ W1l, const float* __restrict__ W1r,
    const float* __restrict__ W2l, const float* __restrict__ W2r,
    unsigned short* __restrict__ Wpack,
    const float* __restrict__ xin, unsigned short* __restrict__ xb, int n4)
{
    if (blockIdx.x < 32) {
        int b = blockIdx.x * 4 + (threadIdx.x >> 6);
        int l = threadIdx.x & 63;
        int layer = b >> 6, wsel = (b >> 5) & 1, kt = (b >> 3) & 3, ct = b & 7;
        const float* W = layer ? (wsel ? W2r : W2l) : (wsel ? W1r : W1l);
        int k0  = kt * 32 + (l >> 4) * 8;
        int col = ct * 16 + (l & 15);
        unsigned short tmp[8];
#pragma unroll
        for (int j = 0; j < 8; ++j) tmp[j] = f2bf(W[(k0 + j) * D + col]);
        size_t fbase = (((size_t)layer * 64 + wsel * 32 + kt * 8 + ct) * 64 + l) * 8;
        uint4 o;
        o.x = (unsigned)tmp[0] | ((unsigned)tmp[1] << 16);
        o.y = (unsigned)tmp[2] | ((unsigned)tmp[3] << 16);
        o.z = (unsigned)tmp[4] | ((unsigned)tmp[5] << 16);
        o.w = (unsigned)tmp[6] | ((unsigned)tmp[7] << 16);
        *reinterpret_cast<uint4*>(Wpack + fbase) = o;
    } else {
        int i = (blockIdx.x - 32) * 256 + threadIdx.x;
        if (i < n4) {
            float4 v = reinterpret_cast<const float4*>(xin)[i];
            ushort4 o;
            o.x = f2bf(v.x); o.y = f2bf(v.y); o.z = f2bf(v.z); o.w = f2bf(v.w);
            reinterpret_cast<ushort4*>(xb)[i] = o;
        }
    }
}

// ---------------------------------------------------------------------------
// 5. Gather-mean in bf16: one wave per node, lane l owns features [2l, 2l+1].
// ---------------------------------------------------------------------------
__global__ __launch_bounds__(256) void gather_bf16(
    const unsigned short* __restrict__ feat, const int* __restrict__ off,
    const int* __restrict__ endp, const int* __restrict__ csr,
    unsigned short* __restrict__ mean, int N)
{
    int tid  = blockIdx.x * 256 + threadIdx.x;
    int n    = tid >> 6;
    int lane = tid & 63;
    if (n >= N) return;
    int b = off[n], e = endp[n];
    const unsigned short* fp = feat + lane * 2;
    float ax = 0.f, ay = 0.f, bx = 0.f, by = 0.f;
    int j = b;
    for (; j + 1 < e; j += 2) {
        unsigned v0 = *reinterpret_cast<const unsigned*>(fp + (size_t)csr[j] * D);
        unsigned v1 = *reinterpret_cast<const unsigned*>(fp + (size_t)csr[j + 1] * D);
        ax += __uint_as_float(v0 << 16);
        ay += __uint_as_float(v0 & 0xffff0000u);
        bx += __uint_as_float(v1 << 16);
        by += __uint_as_float(v1 & 0xffff0000u);
    }
    if (j < e) {
        unsigned v0 = *reinterpret_cast<const unsigned*>(fp + (size_t)csr[j] * D);
        ax += __uint_as_float(v0 << 16);
        ay += __uint_as_float(v0 & 0xffff0000u);
    }
    ax += bx; ay += by;
    float invd = 1.0f / (float)max(e - b, 1);
    ax *= invd; ay *= invd;
    unsigned o = (unsigned)f2bf(ax) | ((unsigned)f2bf(ay) << 16);
    *reinterpret_cast<unsigned*>(mean + (size_t)n * D + lane * 2) = o;
}

// ---------------------------------------------------------------------------
// 6. MFMA SAGE linear: out = [relu]( mean @ Wl + bl + xin @ Wr ), bf16 in.
// ---------------------------------------------------------------------------
template <int RELU, int OUT_BF16>
__global__ __launch_bounds__(256, 2) void sage_mfma(
    const unsigned short* __restrict__ meanb,
    const unsigned short* __restrict__ xb,
    const unsigned short* __restrict__ Wpack,
    const float* __restrict__ bl,
    void* __restrict__ outv, int Mtiles, int TPB)
{
    __shared__ __align__(16) char sbuf[2][8192];
    const int t    = threadIdx.x;
    const int lane = t & 63;
    const int wc   = t >> 6;
    const int l15  = lane & 15;
    const int lhi  = lane >> 4;

    bf16x8 bfrag[2][8];
#pragma unroll
    for (int ktt = 0; ktt < 8; ++ktt) {
        int wsel = ktt >> 2, kt = ktt & 3;
#pragma unroll
        for (int c = 0; c < 2; ++c) {
            int ct = wc * 2 + c;
            size_t fbase = ((size_t)(wsel * 32 + kt * 8 + ct) * 64 + lane) * 8;
            bfrag[c][ktt] = *reinterpret_cast<const bf16x8*>(Wpack + fbase);
        }
    }
    float bias[2];
    bias[0] = bl[wc * 32 + l15];
    bias[1] = bl[wc * 32 + 16 + l15];

    int tile0 = blockIdx.x * TPB;
    if (tile0 >= Mtiles) return;
    int tend = min(tile0 + TPB, Mtiles);

    const int sr = t >> 4;
    const int sq = t & 15;
    const int ss = sq ^ (sr & 7);
    char* dstM = &sbuf[0][sr * 256 + ss * 16];
    char* dstX = &sbuf[0][4096 + sr * 256 + ss * 16];

    {
        size_t gofs = (size_t)(tile0 * 16 + sr) * D + sq * 8;
        *reinterpret_cast<uint4*>(dstM) = *reinterpret_cast<const uint4*>(meanb + gofs);
        *reinterpret_cast<uint4*>(dstX) = *reinterpret_cast<const uint4*>(xb + gofs);
    }
    int cur = 0;

    for (int it = tile0; it < tend; ++it) {
        __syncthreads();
        const bool pf = (it + 1 < tend);
        uint4 mv, xv;
        if (pf) {
            size_t gofs = (size_t)((it + 1) * 16 + sr) * D + sq * 8;
            mv = *reinterpret_cast<const uint4*>(meanb + gofs);
            xv = *reinterpret_cast<const uint4*>(xb + gofs);
        }

        f32x4 acc0 = {0.f, 0.f, 0.f, 0.f};
        f32x4 acc1 = {0.f, 0.f, 0.f, 0.f};
        const char* base = sbuf[cur];
#pragma unroll
        for (int ktt = 0; ktt < 8; ++ktt) {
            int p = ktt >> 2, kt = ktt & 3;
            int q = kt * 4 + lhi;
            int byteoff = p * 4096 + l15 * 256 + ((q ^ (l15 & 7)) * 16);
            bf16x8 a = *reinterpret_cast<const bf16x8*>(base + byteoff);
            acc0 = __builtin_amdgcn_mfma_f32_16x16x32_bf16(a, bfrag[0][ktt], acc0, 0, 0, 0);
            acc1 = __builtin_amdgcn_mfma_f32_16x16x32_bf16(a, bfrag[1][ktt], acc1, 0, 0, 0);
        }

        int rbase = it * 16 + lhi * 4;
#pragma unroll
        for (int c = 0; c < 2; ++c) {
            int col = wc * 32 + c * 16 + l15;
            const f32x4& a = c ? acc1 : acc0;
#pragma unroll
            for (int r = 0; r < 4; ++r) {
                float v = a[r] + bias[c];
                if (RELU) v = fmaxf(v, 0.f);
                if (OUT_BF16) {
                    ((unsigned short*)outv)[(size_t)(rbase + r) * D + col] = f2bf(v);
                } else {
                    ((float*)outv)[(size_t)(rbase + r) * D + col] = v;
                }
            }
        }

        if (pf) {
            char* dM = dstM + (cur ^ 1) * 8192;
            char* dX = dstX + (cur ^ 1) * 8192;
            *reinterpret_cast<uint4*>(dM) = mv;
            *reinterpret_cast<uint4*>(dX) = xv;
            cur ^= 1;
        }
    }
}

extern "C" void kernel_launch(void* const* d_in, const int* in_sizes, int n_in,
                              void* d_out, int out_size, void* d_ws, size_t ws_size,
                              hipStream_t stream) {
    const float* x   = (const float*)d_in[0];
    const int*   ei  = (const int*)d_in[1];
    const float* W1l = (const float*)d_in[2];
    const float* b1l = (const float*)d_in[3];
    const float* W1r = (const float*)d_in[4];
    const float* W2l = (const float*)d_in[5];
    const float* b2l = (const float*)d_in[6];
    const float* W2r = (const float*)d_in[7];
    float* out = (float*)d_out;

    const int N = in_sizes[0] / D;
    const int E = in_sizes[1] / 2;
    const int* src = ei;
    const int* dst = ei + E;

    unsigned short* xb    = (unsigned short*)d_ws;          // N*D bf16
    unsigned short* meanb = xb + (size_t)N * D;             // N*D
    unsigned short* hb    = meanb + (size_t)N * D;          // N*D
    unsigned short* Wpack = hb + (size_t)N * D;             // 65536
    int* deg      = (int*)(Wpack + 65536);                  // N
    int* off      = deg + N;                                // N
    int* cursor   = off + N;                                // N
    int* csr_src  = cursor + N;                             // E
    int* chunkSum = csr_src + E;                            // nChunks

    const int nChunks = (N + CHUNK - 1) / CHUNK;
    const int Mtiles  = (N + 15) / 16;
    const int TPB     = 8;
    const int gemmGrid = (Mtiles + TPB - 1) / TPB;
    const int gatherBlocks = (int)(((long long)N * 64 + 255) / 256);
    const int npg = (N + 7) / 8;
    const int segSpan = 8192;
    const int nSeg = (E + segSpan - 1) / segSpan;

    // --- CSR build ---
    hipMemsetAsync(deg, 0, (size_t)N * sizeof(int), stream);
    hist_kernel<<<(E + 255) / 256, 256, 0, stream>>>(dst, deg, E);
    scanA_kernel<<<nChunks, 256, 0, stream>>>(deg, off, chunkSum, N);
    scanC_kernel<<<(N + 255) / 256, 256, 0, stream>>>(off, cursor, chunkSum, N, nChunks);
    fill8_kernel<<<nSeg * 8, 256, 0, stream>>>(src, dst, cursor, csr_src, E, npg, segSpan);

    // --- precision prep (pack W + convert x) ---
    prep_kernel<<<32 + ((N * D / 4) + 255) / 256, 256, 0, stream>>>(
        W1l, W1r, W2l, W2r, Wpack, x, xb, N * D / 4);

    // --- layer 1 ---
    gather_bf16<<<gatherBlocks, 256, 0, stream>>>(xb, off, cursor, csr_src, meanb, N);
    sage_mfma<1, 1><<<gemmGrid, 256, 0, stream>>>(meanb, xb, Wpack, b1l, hb, Mtiles, TPB);

    // --- layer 2 ---
    gather_bf16<<<gatherBlocks, 256, 0, stream>>>(hb, off, cursor, csr_src, meanb, N);
    sage_mfma<0, 0><<<gemmGrid, 256, 0, stream>>>(meanb, hb, Wpack + 32768, b2l, out, Mtiles, TPB);
}

// Round 5
// 231.481 us; speedup vs baseline: 8.4218x; 1.2137x over previous
//
#include <hip/hip_runtime.h>

#define D 128
constexpr int CHUNK = 2048;

typedef __bf16 bf16x8 __attribute__((ext_vector_type(8)));
typedef float f32x4 __attribute__((ext_vector_type(4)));

__device__ __forceinline__ unsigned short f2bf(float f) {
    unsigned int u = __float_as_uint(f);
    unsigned int r = (u + 0x7fffu + ((u >> 16) & 1u)) >> 16;
    return (unsigned short)r;
}
__device__ __forceinline__ unsigned pack2(float a, float b) {
    return (unsigned)f2bf(a) | ((unsigned)f2bf(b) << 16);
}

// ---------------------------------------------------------------------------
// 1. Degree histogram, XCD-partitioned: group g = blockIdx&7 counts only
//    dst in [g*npg,(g+1)*npg) -> atomic lines stay in one XCD's L2.
// ---------------------------------------------------------------------------
__global__ __launch_bounds__(256) void hist8_kernel(
    const int* __restrict__ dst, int* __restrict__ deg,
    int E, int npg, int segSpan)
{
    const int g   = blockIdx.x & 7;
    const int seg = blockIdx.x >> 3;
    const int lo  = g * npg;
    const int hi  = lo + npg;
    const int e0  = seg * segSpan;
    const int e1  = min(e0 + segSpan, E);
    for (int e = e0 + threadIdx.x; e < e1; e += 256) {
        int d = dst[e];
        if (d >= lo && d < hi) atomicAdd(&deg[d], 1);
    }
}

// ---------------------------------------------------------------------------
// 2a. Per-chunk exclusive scan of deg -> off, chunk totals -> chunkSum
// ---------------------------------------------------------------------------
__global__ __launch_bounds__(256) void scanA_kernel(
    const int* __restrict__ deg, int* __restrict__ off,
    int* __restrict__ chunkSum, int N)
{
    __shared__ int s[256];
    const int t = threadIdx.x;
    const int base = blockIdx.x * CHUNK + t * 8;
    int v[8], sum = 0;
#pragma unroll
    for (int i = 0; i < 8; ++i) {
        int idx = base + i;
        v[i] = (idx < N) ? deg[idx] : 0;
        sum += v[i];
    }
    s[t] = sum;
    __syncthreads();
    for (int o = 1; o < 256; o <<= 1) {
        int y = (t >= o) ? s[t - o] : 0;
        __syncthreads();
        s[t] += y;
        __syncthreads();
    }
    int excl = s[t] - sum;
#pragma unroll
    for (int i = 0; i < 8; ++i) {
        int idx = base + i;
        if (idx < N) off[idx] = excl;
        excl += v[i];
    }
    if (t == 0) chunkSum[blockIdx.x] = s[255];
}

// ---------------------------------------------------------------------------
// 2b. Add chunk prefix (wave-reduce over <=64 chunk sums); final off + cursor.
// ---------------------------------------------------------------------------
__global__ __launch_bounds__(256) void scanC_kernel(
    int* __restrict__ off, int* __restrict__ cursor,
    const int* __restrict__ chunkSum, int N, int nChunks)
{
    __shared__ int sprefix;
    const int c = (blockIdx.x * 256) / CHUNK;
    if (threadIdx.x < 64) {
        int l = threadIdx.x;
        int v = (l < c && l < nChunks) ? chunkSum[l] : 0;
#pragma unroll
        for (int o = 32; o; o >>= 1) v += __shfl_down(v, o, 64);
        if (l == 0) sprefix = v;
    }
    __syncthreads();
    int i = blockIdx.x * 256 + threadIdx.x;
    if (i < N) {
        int o = off[i] + sprefix;
        off[i] = o;
        cursor[i] = o;
    }
}

// ---------------------------------------------------------------------------
// 3. XCD-partitioned CSR fill (round-4, kept).
// ---------------------------------------------------------------------------
__global__ __launch_bounds__(256) void fill8_kernel(
    const int* __restrict__ src, const int* __restrict__ dst,
    int* __restrict__ cursor, int* __restrict__ csr_src,
    int E, int npg, int segSpan)
{
    const int g   = blockIdx.x & 7;
    const int seg = blockIdx.x >> 3;
    const int lo  = g * npg;
    const int hi  = lo + npg;
    const int e0  = seg * segSpan;
    const int e1  = min(e0 + segSpan, E);
    for (int e = e0 + threadIdx.x; e < e1; e += 256) {
        int d = dst[e];
        if (d >= lo && d < hi) {
            int p = atomicAdd(&cursor[d], 1);
            csr_src[p] = src[e];
        }
    }
}

// ---------------------------------------------------------------------------
// 4. Fused prep: blocks [0,32) pack W -> MFMA B-frag bf16; rest convert x.
// ---------------------------------------------------------------------------
__global__ __launch_bounds__(256) void prep_kernel(
    const float* __restrict__ W1l, const float* __restrict__ W1r,
    const float* __restrict__ W2l, const float* __restrict__ W2r,
    unsigned short* __restrict__ Wpack,
    const float* __restrict__ xin, unsigned short* __restrict__ xb, int n4)
{
    if (blockIdx.x < 32) {
        int b = blockIdx.x * 4 + (threadIdx.x >> 6);
        int l = threadIdx.x & 63;
        int layer = b >> 6, wsel = (b >> 5) & 1, kt = (b >> 3) & 3, ct = b & 7;
        const float* W = layer ? (wsel ? W2r : W2l) : (wsel ? W1r : W1l);
        int k0  = kt * 32 + (l >> 4) * 8;
        int col = ct * 16 + (l & 15);
        unsigned short tmp[8];
#pragma unroll
        for (int j = 0; j < 8; ++j) tmp[j] = f2bf(W[(k0 + j) * D + col]);
        size_t fbase = (((size_t)layer * 64 + wsel * 32 + kt * 8 + ct) * 64 + l) * 8;
        uint4 o;
        o.x = (unsigned)tmp[0] | ((unsigned)tmp[1] << 16);
        o.y = (unsigned)tmp[2] | ((unsigned)tmp[3] << 16);
        o.z = (unsigned)tmp[4] | ((unsigned)tmp[5] << 16);
        o.w = (unsigned)tmp[6] | ((unsigned)tmp[7] << 16);
        *reinterpret_cast<uint4*>(Wpack + fbase) = o;
    } else {
        int i = (blockIdx.x - 32) * 256 + threadIdx.x;
        if (i < n4) {
            float4 v = reinterpret_cast<const float4*>(xin)[i];
            ushort4 o;
            o.x = f2bf(v.x); o.y = f2bf(v.y); o.z = f2bf(v.z); o.w = f2bf(v.w);
            reinterpret_cast<ushort4*>(xb)[i] = o;
        }
    }
}

// ---------------------------------------------------------------------------
// 5. Gather-mean, 4 nodes/wave: 16 lanes per node, lane q loads the uint4
//    (8 bf16) slice [8q..8q+7] of each neighbor row. 4 independent edge
//    streams per wave + unroll x2 -> 8x the outstanding bytes of round 4.
// ---------------------------------------------------------------------------
__global__ __launch_bounds__(256) void gather4_bf16(
    const unsigned short* __restrict__ feat, const int* __restrict__ off,
    const int* __restrict__ endp, const int* __restrict__ csr,
    unsigned short* __restrict__ mean, int N)
{
    int tid = blockIdx.x * 256 + threadIdx.x;
    int n   = tid >> 4;
    int q   = tid & 15;
    if (n >= N) return;
    int b = off[n], e = endp[n];
    const uint4* fp = reinterpret_cast<const uint4*>(feat) + q;  // +16B per q

    float acc[8];
#pragma unroll
    for (int i = 0; i < 8; ++i) acc[i] = 0.f;

    int j = b;
    for (; j + 1 < e; j += 2) {
        int s0 = csr[j];
        int s1 = csr[j + 1];
        uint4 v0 = fp[(size_t)s0 * 16];
        uint4 v1 = fp[(size_t)s1 * 16];
        const unsigned* u0 = &v0.x;
        const unsigned* u1 = &v1.x;
#pragma unroll
        for (int i = 0; i < 4; ++i) {
            acc[2 * i]     += __uint_as_float(u0[i] << 16);
            acc[2 * i + 1] += __uint_as_float(u0[i] & 0xffff0000u);
            acc[2 * i]     += __uint_as_float(u1[i] << 16);
            acc[2 * i + 1] += __uint_as_float(u1[i] & 0xffff0000u);
        }
    }
    if (j < e) {
        uint4 v0 = fp[(size_t)csr[j] * 16];
        const unsigned* u0 = &v0.x;
#pragma unroll
        for (int i = 0; i < 4; ++i) {
            acc[2 * i]     += __uint_as_float(u0[i] << 16);
            acc[2 * i + 1] += __uint_as_float(u0[i] & 0xffff0000u);
        }
    }
    float invd = 1.0f / (float)max(e - b, 1);
#pragma unroll
    for (int i = 0; i < 8; ++i) acc[i] *= invd;
    uint4 o;
    o.x = pack2(acc[0], acc[1]);
    o.y = pack2(acc[2], acc[3]);
    o.z = pack2(acc[4], acc[5]);
    o.w = pack2(acc[6], acc[7]);
    *reinterpret_cast<uint4*>(mean + (size_t)n * D + q * 8) = o;
}

// ---------------------------------------------------------------------------
// 6. MFMA SAGE linear: out = [relu]( mean @ Wl + bl + xin @ Wr ), bf16 in.
// ---------------------------------------------------------------------------
template <int RELU, int OUT_BF16>
__global__ __launch_bounds__(256, 2) void sage_mfma(
    const unsigned short* __restrict__ meanb,
    const unsigned short* __restrict__ xb,
    const unsigned short* __restrict__ Wpack,
    const float* __restrict__ bl,
    void* __restrict__ outv, int Mtiles, int TPB)
{
    __shared__ __align__(16) char sbuf[2][8192];
    const int t    = threadIdx.x;
    const int lane = t & 63;
    const int wc   = t >> 6;
    const int l15  = lane & 15;
    const int lhi  = lane >> 4;

    bf16x8 bfrag[2][8];
#pragma unroll
    for (int ktt = 0; ktt < 8; ++ktt) {
        int wsel = ktt >> 2, kt = ktt & 3;
#pragma unroll
        for (int c = 0; c < 2; ++c) {
            int ct = wc * 2 + c;
            size_t fbase = ((size_t)(wsel * 32 + kt * 8 + ct) * 64 + lane) * 8;
            bfrag[c][ktt] = *reinterpret_cast<const bf16x8*>(Wpack + fbase);
        }
    }
    float bias[2];
    bias[0] = bl[wc * 32 + l15];
    bias[1] = bl[wc * 32 + 16 + l15];

    int tile0 = blockIdx.x * TPB;
    if (tile0 >= Mtiles) return;
    int tend = min(tile0 + TPB, Mtiles);

    const int sr = t >> 4;
    const int sq = t & 15;
    const int ss = sq ^ (sr & 7);
    char* dstM = &sbuf[0][sr * 256 + ss * 16];
    char* dstX = &sbuf[0][4096 + sr * 256 + ss * 16];

    {
        size_t gofs = (size_t)(tile0 * 16 + sr) * D + sq * 8;
        *reinterpret_cast<uint4*>(dstM) = *reinterpret_cast<const uint4*>(meanb + gofs);
        *reinterpret_cast<uint4*>(dstX) = *reinterpret_cast<const uint4*>(xb + gofs);
    }
    int cur = 0;

    for (int it = tile0; it < tend; ++it) {
        __syncthreads();
        const bool pf = (it + 1 < tend);
        uint4 mv, xv;
        if (pf) {
            size_t gofs = (size_t)((it + 1) * 16 + sr) * D + sq * 8;
            mv = *reinterpret_cast<const uint4*>(meanb + gofs);
            xv = *reinterpret_cast<const uint4*>(xb + gofs);
        }

        f32x4 acc0 = {0.f, 0.f, 0.f, 0.f};
        f32x4 acc1 = {0.f, 0.f, 0.f, 0.f};
        const char* base = sbuf[cur];
#pragma unroll
        for (int ktt = 0; ktt < 8; ++ktt) {
            int p = ktt >> 2, kt = ktt & 3;
            int q = kt * 4 + lhi;
            int byteoff = p * 4096 + l15 * 256 + ((q ^ (l15 & 7)) * 16);
            bf16x8 a = *reinterpret_cast<const bf16x8*>(base + byteoff);
            acc0 = __builtin_amdgcn_mfma_f32_16x16x32_bf16(a, bfrag[0][ktt], acc0, 0, 0, 0);
            acc1 = __builtin_amdgcn_mfma_f32_16x16x32_bf16(a, bfrag[1][ktt], acc1, 0, 0, 0);
        }

        int rbase = it * 16 + lhi * 4;
#pragma unroll
        for (int c = 0; c < 2; ++c) {
            int col = wc * 32 + c * 16 + l15;
            const f32x4& a = c ? acc1 : acc0;
#pragma unroll
            for (int r = 0; r < 4; ++r) {
                float v = a[r] + bias[c];
                if (RELU) v = fmaxf(v, 0.f);
                if (OUT_BF16) {
                    ((unsigned short*)outv)[(size_t)(rbase + r) * D + col] = f2bf(v);
                } else {
                    ((float*)outv)[(size_t)(rbase + r) * D + col] = v;
                }
            }
        }

        if (pf) {
            char* dM = dstM + (cur ^ 1) * 8192;
            char* dX = dstX + (cur ^ 1) * 8192;
            *reinterpret_cast<uint4*>(dM) = mv;
            *reinterpret_cast<uint4*>(dX) = xv;
            cur ^= 1;
        }
    }
}

extern "C" void kernel_launch(void* const* d_in, const int* in_sizes, int n_in,
                              void* d_out, int out_size, void* d_ws, size_t ws_size,
                              hipStream_t stream) {
    const float* x   = (const float*)d_in[0];
    const int*   ei  = (const int*)d_in[1];
    const float* W1l = (const float*)d_in[2];
    const float* b1l = (const float*)d_in[3];
    const float* W1r = (const float*)d_in[4];
    const float* W2l = (const float*)d_in[5];
    const float* b2l = (const float*)d_in[6];
    const float* W2r = (const float*)d_in[7];
    float* out = (float*)d_out;

    const int N = in_sizes[0] / D;
    const int E = in_sizes[1] / 2;
    const int* src = ei;
    const int* dst = ei + E;

    unsigned short* xb    = (unsigned short*)d_ws;          // N*D bf16
    unsigned short* meanb = xb + (size_t)N * D;             // N*D
    unsigned short* hb    = meanb + (size_t)N * D;          // N*D
    unsigned short* Wpack = hb + (size_t)N * D;             // 65536
    int* deg      = (int*)(Wpack + 65536);                  // N
    int* off      = deg + N;                                // N
    int* cursor   = off + N;                                // N
    int* csr_src  = cursor + N;                             // E
    int* chunkSum = csr_src + E;                            // nChunks

    const int nChunks = (N + CHUNK - 1) / CHUNK;
    const int Mtiles  = (N + 15) / 16;
    const int TPB     = 8;
    const int gemmGrid = (Mtiles + TPB - 1) / TPB;
    const int gatherBlocks = (int)(((long long)N * 16 + 255) / 256);
    const int npg = (N + 7) / 8;
    const int segSpan = 8192;
    const int nSeg = (E + segSpan - 1) / segSpan;

    // --- CSR build ---
    hipMemsetAsync(deg, 0, (size_t)N * sizeof(int), stream);
    hist8_kernel<<<nSeg * 8, 256, 0, stream>>>(dst, deg, E, npg, segSpan);
    scanA_kernel<<<nChunks, 256, 0, stream>>>(deg, off, chunkSum, N);
    scanC_kernel<<<(N + 255) / 256, 256, 0, stream>>>(off, cursor, chunkSum, N, nChunks);
    fill8_kernel<<<nSeg * 8, 256, 0, stream>>>(src, dst, cursor, csr_src, E, npg, segSpan);

    // --- precision prep (pack W + convert x) ---
    prep_kernel<<<32 + ((N * D / 4) + 255) / 256, 256, 0, stream>>>(
        W1l, W1r, W2l, W2r, Wpack, x, xb, N * D / 4);

    // --- layer 1 ---
    gather4_bf16<<<gatherBlocks, 256, 0, stream>>>(xb, off, cursor, csr_src, meanb, N);
    sage_mfma<1, 1><<<gemmGrid, 256, 0, stream>>>(meanb, xb, Wpack, b1l, hb, Mtiles, TPB);

    // --- layer 2 ---
    gather4_bf16<<<gatherBlocks, 256, 0, stream>>>(hb, off, cursor, csr_src, meanb, N);
    sage_mfma<0, 0><<<gemmGrid, 256, 0, stream>>>(meanb, hb, Wpack + 32768, b2l, out, Mtiles, TPB);
}